// Round 5
// baseline (566.949 us; speedup 1.0000x reference)
//
#include <hip/hip_runtime.h>

typedef float f32x4 __attribute__((ext_vector_type(4)));
typedef __bf16 bf16x8 __attribute__((ext_vector_type(8)));
typedef unsigned int u32x4 __attribute__((ext_vector_type(4)));
typedef unsigned short ushort_t;

// ---------------------------------------------------------------- fp32 -> bf16 (RNE)
__device__ __forceinline__ unsigned short f2bf(float f) {
    unsigned u = __float_as_uint(f);
    u += 0x7FFFu + ((u >> 16) & 1u);   // round-nearest-even (inputs finite)
    return (unsigned short)(u >> 16);
}

// W-only cast kernel (x-cast is now fused into the GEMM's A-staging).
// NT loads: R3 vs R4 A/B showed NT >= plain for this kernel.
__global__ __launch_bounds__(256) void cast_w(const f32x4* __restrict__ w, u32x4* __restrict__ wo) {
    long j = (long)blockIdx.x * 256 + threadIdx.x;    // 2097152 threads
    f32x4 a = __builtin_nontemporal_load(&w[2 * j]);
    f32x4 b = __builtin_nontemporal_load(&w[2 * j + 1]);
    u32x4 v;
    v.x = (unsigned)f2bf(a.x) | ((unsigned)f2bf(a.y) << 16);
    v.y = (unsigned)f2bf(a.z) | ((unsigned)f2bf(a.w) << 16);
    v.z = (unsigned)f2bf(b.x) | ((unsigned)f2bf(b.y) << 16);
    v.w = (unsigned)f2bf(b.z) | ((unsigned)f2bf(b.w) << 16);
    wo[j] = v;
}

// ---------------------------------------------------------------- 256x256 8-phase bf16 MFMA GEMM
// A read as FP32 and converted during staging (fused x-cast); B (=W) precast bf16.
// Skeleton = R1/R3 verified structure (0 bank conflicts, 16x16x32 shape, XOR 16B-slot swizzle).
// Per tile t (buffer b = t&1):
//   p0: ds_read av(A0[b]), bv(B0[b]); gload_lds B0(t+1)->ob; issue 4xf32 loads A0(t+2)->rA0
//       barrier; Q(0,0)=av.bv; barrier
//   p1: ds_read bv2(B1[b]); issue A1(t+2)->rA1; barrier; Q(0,1)=av.bv2; barrier
//   p2: ds_read av(A1[b]); cvt+ds_write rA0 -> A0[b]; gload_lds B1(t+2)->b
//       barrier; Q(1,1)=av.bv2; barrier
//   p3: cvt+ds_write rA1 -> A1[b]; barrier; Q(1,0)=av.bv; barrier
// WAR: A0[b] written @p2 (last read p0-done-by-barrier); A1[b] @p3 (last read p2);
//      B1[b] gload @p2 (last read p1).  RAW for B glds: each wave's p2/p3 cvt forces a
//      vmcnt wait retiring all older glds; barrier => cross-wave visible.  No explicit
//      vmcnt needed in steady state; drain tiles 62/63 use vmcnt(0).
constexpr int KD = 4096;

#define GLOAD_LDS(gp, lp) __builtin_amdgcn_global_load_lds( \
    (const __attribute__((address_space(1))) unsigned int*)(gp), \
    (__attribute__((address_space(3))) unsigned int*)(lp), 16, 0, 0)

#define BARRIER() do { asm volatile("" ::: "memory"); __builtin_amdgcn_s_barrier(); \
                       asm volatile("" ::: "memory"); } while (0)
#define WAIT_VM(n)   asm volatile("s_waitcnt vmcnt(" #n ")" ::: "memory")

__global__ __launch_bounds__(512, 2) void gemm256(const float* __restrict__ A,
                                                  const ushort_t* __restrict__ B,
                                                  const float* __restrict__ bias,
                                                  float* __restrict__ out) {
    __shared__ char lds[131072];
    // A half-tiles at (buf*2+half)*16384, B half-tiles at 65536 + (buf*2+half)*16384

    const int tid  = threadIdx.x;
    const int lane = tid & 63;
    const int wave = tid >> 6;      // 0..7
    const int wr   = wave >> 2;     // 0..1  (M)
    const int wc   = wave & 3;      // 0..3  (N)
    const int q    = lane >> 4;
    const int ml   = lane & 15;

    // XCD-aware bijective swizzle (512 blocks % 8 == 0)
    const int bid = blockIdx.x;
    const int swz = (bid & 7) * 64 + (bid >> 3);
    const int m0  = (swz >> 4) * 256;
    const int n0  = (swz & 15) * 256;

    // staging: slot c = tid&7 of row srow holds source 16B-bf16-block c ^ (srow&7)
    const int srow = tid >> 3;
    const int koff = ((tid & 7) ^ (srow & 7)) * 8;   // element offset along K
    const int ldst = tid * 16;
    const float*    gAf = A + (size_t)m0 * KD + koff;
    const ushort_t* gB  = B + (size_t)n0 * KD + koff;

#define STAGE_B(buf, half, kt) do { \
    const ushort_t* _g = gB + (size_t)((half) * 128 + srow) * KD + (kt); \
    char* _l = lds + 65536 + ((buf) * 2 + (half)) * 16384 + ldst; \
    GLOAD_LDS(_g, _l); \
    GLOAD_LDS(_g + (size_t)64 * KD, _l + 8192); \
} while (0)

    // A staging: issue 4 dwordx4 f32 loads (2 slots x 32B) for half h of K-tile kt
#define A_ISSUE(R0, R1, R2, R3, h, kt) do { \
    const float* _g = gAf + (size_t)((h) * 128 + srow) * KD + (kt); \
    R0 = *(const f32x4*)(_g); \
    R1 = *(const f32x4*)(_g + 4); \
    R2 = *(const f32x4*)(_g + (size_t)64 * KD); \
    R3 = *(const f32x4*)(_g + (size_t)64 * KD + 4); \
} while (0)

    // convert + ds_write the two 16B bf16 slots.  The asm pin forces the cvts (register-
    // only ops the barriers can't order) to stay HERE, so their implicit vmcnt wait
    // doesn't get hoisted into the issue phase.
#define A_WRITE(R0, R1, R2, R3, buf, h) do { \
    asm volatile("" : "+v"(R0), "+v"(R1), "+v"(R2), "+v"(R3)); \
    char* _l = lds + ((buf) * 2 + (h)) * 16384 + ldst; \
    bf16x8 _v0, _v1; \
    _v0[0] = (__bf16)R0.x; _v0[1] = (__bf16)R0.y; _v0[2] = (__bf16)R0.z; _v0[3] = (__bf16)R0.w; \
    _v0[4] = (__bf16)R1.x; _v0[5] = (__bf16)R1.y; _v0[6] = (__bf16)R1.z; _v0[7] = (__bf16)R1.w; \
    _v1[0] = (__bf16)R2.x; _v1[1] = (__bf16)R2.y; _v1[2] = (__bf16)R2.z; _v1[3] = (__bf16)R2.w; \
    _v1[4] = (__bf16)R3.x; _v1[5] = (__bf16)R3.y; _v1[6] = (__bf16)R3.z; _v1[7] = (__bf16)R3.w; \
    *(bf16x8*)(_l)        = _v0; \
    *(bf16x8*)(_l + 8192) = _v1; \
} while (0)

    // fragment read byte-offsets within a 16KB half-tile (row&7 == ml&7 for all rows)
    int offA[4][2], offB[2][2];
#pragma unroll
    for (int mi = 0; mi < 4; ++mi)
#pragma unroll
        for (int s = 0; s < 2; ++s)
            offA[mi][s] = (wr * 64 + mi * 16 + ml) * 128 + (((s * 4 + q) ^ (ml & 7)) << 4);
#pragma unroll
    for (int nj = 0; nj < 2; ++nj)
#pragma unroll
        for (int s = 0; s < 2; ++s)
            offB[nj][s] = (wc * 32 + nj * 16 + ml) * 128 + (((s * 4 + q) ^ (ml & 7)) << 4);

    f32x4 acc[2][2][4][2];
#pragma unroll
    for (int a = 0; a < 2; ++a)
#pragma unroll
        for (int c = 0; c < 2; ++c)
#pragma unroll
            for (int d = 0; d < 4; ++d)
#pragma unroll
                for (int e = 0; e < 2; ++e) {
                    acc[a][c][d][e].x = 0.f; acc[a][c][d][e].y = 0.f;
                    acc[a][c][d][e].z = 0.f; acc[a][c][d][e].w = 0.f;
                }

    bf16x8 av[4][2], bv[2][2], bv2[2][2];
    f32x4 a0r0, a0r1, a0r2, a0r3;   // A-half0(t+2) in flight
    f32x4 a1r0, a1r1, a1r2, a1r3;   // A-half1(t+2) in flight

#define LOAD_AV(bI, mh) do { \
    const char* _b = lds + ((bI) * 2 + (mh)) * 16384; \
    _Pragma("unroll") for (int mi = 0; mi < 4; ++mi) \
    _Pragma("unroll") for (int s = 0; s < 2; ++s) \
        av[mi][s] = *(const bf16x8*)(_b + offA[mi][s]); \
} while (0)

#define LOAD_BV(dst, bI, nh) do { \
    const char* _b = lds + 65536 + ((bI) * 2 + (nh)) * 16384; \
    _Pragma("unroll") for (int nj = 0; nj < 2; ++nj) \
    _Pragma("unroll") for (int s = 0; s < 2; ++s) \
        dst[nj][s] = *(const bf16x8*)(_b + offB[nj][s]); \
} while (0)

#define MFMA_Q(bvv, mh, nh) do { \
    __builtin_amdgcn_s_setprio(1); \
    _Pragma("unroll") for (int s = 0; s < 2; ++s) \
    _Pragma("unroll") for (int mi = 0; mi < 4; ++mi) \
    _Pragma("unroll") for (int nj = 0; nj < 2; ++nj) \
        acc[mh][nh][mi][nj] = __builtin_amdgcn_mfma_f32_16x16x32_bf16(av[mi][s], bvv[nj][s], acc[mh][nh][mi][nj], 0, 0, 0); \
    __builtin_amdgcn_s_setprio(0); \
} while (0)

// DO_A: stage A(t+2) (issue p0/p1, write p2/p3).  DO_B0: gload B0(t+1)->oI at p0.
// DO_B1: gload B1(t+2)->bI at p2.  VMW: extra drain at p3 (tile 62 only).
#define TILE(bI, oI, DO_B0, ktB0, DO_A, ktA, DO_B1, ktB1, VMW) do { \
    LOAD_AV(bI, 0); LOAD_BV(bv, bI, 0); \
    if (DO_B0) { STAGE_B(oI, 0, ktB0); } \
    if (DO_A)  { A_ISSUE(a0r0, a0r1, a0r2, a0r3, 0, ktA); } \
    BARRIER(); MFMA_Q(bv, 0, 0); BARRIER(); \
    LOAD_BV(bv2, bI, 1); \
    if (DO_A)  { A_ISSUE(a1r0, a1r1, a1r2, a1r3, 1, ktA); } \
    BARRIER(); MFMA_Q(bv2, 0, 1); BARRIER(); \
    LOAD_AV(bI, 1); \
    if (DO_A)  { A_WRITE(a0r0, a0r1, a0r2, a0r3, bI, 0); } \
    if (DO_B1) { STAGE_B(bI, 1, ktB1); } \
    BARRIER(); MFMA_Q(bv2, 1, 1); BARRIER(); \
    if (DO_A)  { A_WRITE(a1r0, a1r1, a1r2, a1r3, bI, 1); } \
    VMW; \
    BARRIER(); MFMA_Q(bv, 1, 0); BARRIER(); \
} while (0)

    // prologue: A of tiles 0,1 via fused path (writes wait on their own loads);
    // B0(t0), B1(t0), B1(t1) via gload (B0(t1) comes at t0-p0); drain; barrier.
    A_ISSUE(a0r0, a0r1, a0r2, a0r3, 0, 0);
    A_ISSUE(a1r0, a1r1, a1r2, a1r3, 1, 0);
    A_WRITE(a0r0, a0r1, a0r2, a0r3, 0, 0);
    A_WRITE(a1r0, a1r1, a1r2, a1r3, 0, 1);
    A_ISSUE(a0r0, a0r1, a0r2, a0r3, 0, 64);
    A_ISSUE(a1r0, a1r1, a1r2, a1r3, 1, 64);
    A_WRITE(a0r0, a0r1, a0r2, a0r3, 1, 0);
    A_WRITE(a1r0, a1r1, a1r2, a1r3, 1, 1);
    STAGE_B(0, 0, 0); STAGE_B(0, 1, 0); STAGE_B(1, 1, 64);
    WAIT_VM(0);
    BARRIER();

    // tiles 0..61: full staging.  62: only B0(63) + drain.  63: pure compute.
#pragma unroll 1
    for (int tp = 0; tp < 31; ++tp) {
        const int kt = tp * 128;
        TILE(0, 1, 1, kt + 64,  1, kt + 128, 1, kt + 128, (void)0);
        TILE(1, 0, 1, kt + 128, 1, kt + 192, 1, kt + 192, (void)0);
    }
    TILE(0, 1, 1, 4032, 0, 0, 0, 0, WAIT_VM(0));
    TILE(1, 0, 0, 0,    0, 0, 0, 0, (void)0);

    // epilogue: C/D layout col=lane&15, row=q*4+reg (verified)
    float bb[2][2];
#pragma unroll
    for (int nh = 0; nh < 2; ++nh)
#pragma unroll
        for (int nj = 0; nj < 2; ++nj)
            bb[nh][nj] = bias[n0 + nh * 128 + wc * 32 + nj * 16 + ml];

#pragma unroll
    for (int mh = 0; mh < 2; ++mh)
#pragma unroll
        for (int nh = 0; nh < 2; ++nh)
#pragma unroll
            for (int mi = 0; mi < 4; ++mi)
#pragma unroll
                for (int nj = 0; nj < 2; ++nj) {
                    const int gc  = n0 + nh * 128 + wc * 32 + nj * 16 + ml;
                    const int gr0 = m0 + mh * 128 + wr * 64 + mi * 16 + q * 4;
#pragma unroll
                    for (int r = 0; r < 4; ++r)
                        out[(size_t)(gr0 + r) * 4096 + gc] = acc[mh][nh][mi][nj][r] + bb[nh][nj];
                }
}

// ---------------------------------------------------------------- fp32 fallback (only if ws too small)
__global__ __launch_bounds__(256) void gemm_f32_fallback(const float* __restrict__ x,
                                                         const float* __restrict__ W,
                                                         const float* __restrict__ bias,
                                                         float* __restrict__ out) {
    __shared__ float As[32][33];
    __shared__ float Bs[32][33];
    const int tx = threadIdx.x & 31, ty = threadIdx.x >> 5;   // ty 0..7
    const int m0 = blockIdx.y * 32, n0 = blockIdx.x * 32;
    float acc[4] = {0.f, 0.f, 0.f, 0.f};
    for (int k0 = 0; k0 < 4096; k0 += 32) {
#pragma unroll
        for (int i = 0; i < 4; ++i) {
            As[ty + 8 * i][tx] = x[(size_t)(m0 + ty + 8 * i) * 4096 + k0 + tx];
            Bs[ty + 8 * i][tx] = W[(size_t)(n0 + ty + 8 * i) * 4096 + k0 + tx];
        }
        __syncthreads();
#pragma unroll 8
        for (int kk = 0; kk < 32; ++kk) {
            const float bv_ = Bs[tx][kk];
#pragma unroll
            for (int i = 0; i < 4; ++i) acc[i] += As[ty + 8 * i][kk] * bv_;
        }
        __syncthreads();
    }
#pragma unroll
    for (int i = 0; i < 4; ++i)
        out[(size_t)(m0 + ty + 8 * i) * 4096 + n0 + tx] = acc[i] + bias[n0 + tx];
}

// ---------------------------------------------------------------- launch
extern "C" void kernel_launch(void* const* d_in, const int* in_sizes, int n_in,
                              void* d_out, int out_size, void* d_ws, size_t ws_size,
                              hipStream_t stream) {
    const float* x = (const float*)d_in[0];   // [8192, 4096]
    const float* W = (const float*)d_in[1];   // [4096, 4096]
    const float* b = (const float*)d_in[2];   // [4096]
    float* out = (float*)d_out;               // [8192, 4096]

    constexpr size_t T = 8192, DIN = 4096, DOUT = 4096;
    const size_t nw = DOUT * DIN;

    if (ws_size >= nw * sizeof(unsigned short)) {
        unsigned short* wbf = (unsigned short*)d_ws;
        // W-only cast: 16777216 floats -> 2097152 threads -> 8192 blocks
        cast_w<<<8192, 256, 0, stream>>>((const f32x4*)W, (u32x4*)wbf);
        // 256x256 tiles: 32 x 16 = 512 blocks, 512 threads; A read as f32 (fused cast)
        gemm256<<<512, 512, 0, stream>>>(x, wbf, b, out);
    } else {
        dim3 grid(DOUT / 32, T / 32);
        gemm_f32_fallback<<<grid, 256, 0, stream>>>(x, W, b, out);
    }
}

// Round 6
// 460.522 us; speedup vs baseline: 1.2311x; 1.2311x over previous
//
#include <hip/hip_runtime.h>

typedef float f32x4 __attribute__((ext_vector_type(4)));
typedef __bf16 bf16x8 __attribute__((ext_vector_type(8)));
typedef unsigned int u32x4 __attribute__((ext_vector_type(4)));
typedef unsigned short ushort_t;

// ---------------------------------------------------------------- fp32 -> bf16 (RNE)
__device__ __forceinline__ unsigned short f2bf(float f) {
    unsigned u = __float_as_uint(f);
    u += 0x7FFFu + ((u >> 16) & 1u);   // round-nearest-even (inputs finite)
    return (unsigned short)(u >> 16);
}

// One fused cast kernel for both x and W (R3 verified form; cast ~= 69us, near 48us roofline).
__global__ __launch_bounds__(256) void cast_both(const f32x4* __restrict__ x, u32x4* __restrict__ xo,
                                                 const f32x4* __restrict__ w, u32x4* __restrict__ wo) {
    long t = (long)blockIdx.x * 256 + threadIdx.x;
    const f32x4* src;
    u32x4* dst;
    long j;
    if (t < 4194304L) { src = x; dst = xo; j = t; }
    else              { src = w; dst = wo; j = t - 4194304L; }
    f32x4 a = __builtin_nontemporal_load(&src[2 * j]);
    f32x4 b = __builtin_nontemporal_load(&src[2 * j + 1]);
    u32x4 v;
    v.x = (unsigned)f2bf(a.x) | ((unsigned)f2bf(a.y) << 16);
    v.y = (unsigned)f2bf(a.z) | ((unsigned)f2bf(a.w) << 16);
    v.z = (unsigned)f2bf(b.x) | ((unsigned)f2bf(b.y) << 16);
    v.w = (unsigned)f2bf(b.z) | ((unsigned)f2bf(b.w) << 16);
    dst[j] = v;
}

// ---------------------------------------------------------------- 256x256 bf16 MFMA GEMM
// R3 verified skeleton (passed, 0 bank conflicts, 239us) with ONE change:
// SINGLE barrier per phase (4/tile instead of 8).  The post-MFMA barrier is redundant:
//   - read-vs-write WAR: all ds_reads of a region are ISSUED pre-barrier; any clobbering
//     write (ds or gload_lds-land) is issued post-release -> per-bank arrival order gives
//     the read old data.  Region schedule keeps >=1-phase stage-to-last-read slack anyway
//     (A0 read t-1p3 / staged p1; A1 read p1 / staged p3; B1 read p0 / staged p2;
//      B0 read t-2p3 / staged p0).
//   - staged-RAW: vmcnt(6)@p3 retires ALL of tile t+1's stages (FIFO accounting unchanged),
//     then the p3 barrier publishes before any wave reads buffer oI.
// Effect: waves phase-stagger -- one wave's MFMA overlaps another's ds_read/stage burst
// instead of lockstep {all-read, all-MFMA} alternation.
constexpr int KD = 4096;

#define GLOAD_LDS(gp, lp) __builtin_amdgcn_global_load_lds( \
    (const __attribute__((address_space(1))) unsigned int*)(gp), \
    (__attribute__((address_space(3))) unsigned int*)(lp), 16, 0, 0)

#define BARRIER() do { asm volatile("" ::: "memory"); __builtin_amdgcn_s_barrier(); \
                       asm volatile("" ::: "memory"); } while (0)
#define WAIT_VM(n)   asm volatile("s_waitcnt vmcnt(" #n ")" ::: "memory")

__global__ __launch_bounds__(512, 2) void gemm256(const ushort_t* __restrict__ A,
                                                  const ushort_t* __restrict__ B,
                                                  const float* __restrict__ bias,
                                                  float* __restrict__ out) {
    __shared__ char lds[131072];
    // A half-tiles at (buf*2+half)*16384, B half-tiles at 65536 + (buf*2+half)*16384

    const int tid  = threadIdx.x;
    const int lane = tid & 63;
    const int wave = tid >> 6;      // 0..7
    const int wr   = wave >> 2;     // 0..1  (M)
    const int wc   = wave & 3;      // 0..3  (N)
    const int q    = lane >> 4;
    const int ml   = lane & 15;

    // XCD-aware bijective swizzle (512 blocks % 8 == 0)
    const int bid = blockIdx.x;
    const int swz = (bid & 7) * 64 + (bid >> 3);
    const int m0  = (swz >> 4) * 256;
    const int n0  = (swz & 15) * 256;

    // staging: slot c = tid&7 of row srow holds source 16B-block c ^ (srow&7)
    const int srow = tid >> 3;
    const int koff = ((tid & 7) ^ (srow & 7)) * 8;
    const int ldst = tid * 16;
    const ushort_t* gA = A + (size_t)m0 * KD + koff;
    const ushort_t* gB = B + (size_t)n0 * KD + koff;

#define STAGE_A(buf, half, kt) do { \
    const ushort_t* _g = gA + (size_t)((half) * 128 + srow) * KD + (kt); \
    char* _l = lds + ((buf) * 2 + (half)) * 16384 + ldst; \
    GLOAD_LDS(_g, _l); \
    GLOAD_LDS(_g + (size_t)64 * KD, _l + 8192); \
} while (0)

#define STAGE_B(buf, half, kt) do { \
    const ushort_t* _g = gB + (size_t)((half) * 128 + srow) * KD + (kt); \
    char* _l = lds + 65536 + ((buf) * 2 + (half)) * 16384 + ldst; \
    GLOAD_LDS(_g, _l); \
    GLOAD_LDS(_g + (size_t)64 * KD, _l + 8192); \
} while (0)

    // fragment read byte-offsets within a 16KB half-tile (row&7 == ml&7 for all rows)
    int offA[4][2], offB[2][2];
#pragma unroll
    for (int mi = 0; mi < 4; ++mi)
#pragma unroll
        for (int s = 0; s < 2; ++s)
            offA[mi][s] = (wr * 64 + mi * 16 + ml) * 128 + (((s * 4 + q) ^ (ml & 7)) << 4);
#pragma unroll
    for (int nj = 0; nj < 2; ++nj)
#pragma unroll
        for (int s = 0; s < 2; ++s)
            offB[nj][s] = (wc * 32 + nj * 16 + ml) * 128 + (((s * 4 + q) ^ (ml & 7)) << 4);

    f32x4 acc[2][2][4][2];
#pragma unroll
    for (int a = 0; a < 2; ++a)
#pragma unroll
        for (int c = 0; c < 2; ++c)
#pragma unroll
            for (int d = 0; d < 4; ++d)
#pragma unroll
                for (int e = 0; e < 2; ++e) {
                    acc[a][c][d][e].x = 0.f; acc[a][c][d][e].y = 0.f;
                    acc[a][c][d][e].z = 0.f; acc[a][c][d][e].w = 0.f;
                }

    bf16x8 av0[4][2], av1[4][2], bv0[2][2], bv1[2][2];

#define LOAD_AV(dst, bI, mh) do { \
    const char* _b = lds + ((bI) * 2 + (mh)) * 16384; \
    _Pragma("unroll") for (int mi = 0; mi < 4; ++mi) \
    _Pragma("unroll") for (int s = 0; s < 2; ++s) \
        dst[mi][s] = *(const bf16x8*)(_b + offA[mi][s]); \
} while (0)

#define LOAD_BV(dst, bI, nh) do { \
    const char* _b = lds + 65536 + ((bI) * 2 + (nh)) * 16384; \
    _Pragma("unroll") for (int nj = 0; nj < 2; ++nj) \
    _Pragma("unroll") for (int s = 0; s < 2; ++s) \
        dst[nj][s] = *(const bf16x8*)(_b + offB[nj][s]); \
} while (0)

#define MFMA_Q(av, bv, mh, nh) do { \
    __builtin_amdgcn_s_setprio(1); \
    _Pragma("unroll") for (int s = 0; s < 2; ++s) \
    _Pragma("unroll") for (int mi = 0; mi < 4; ++mi) \
    _Pragma("unroll") for (int nj = 0; nj < 2; ++nj) \
        acc[mh][nh][mi][nj] = __builtin_amdgcn_mfma_f32_16x16x32_bf16(av[mi][s], bv[nj][s], acc[mh][nh][mi][nj], 0, 0, 0); \
    __builtin_amdgcn_s_setprio(0); \
} while (0)

// One K-tile on buffer index bI (0/1), next-tile buffer oI.
// BVLO holds this tile's B-half0 (prefetched at prev p3); BVHI is free on entry.
// Entering: av0 holds this tile's A-half0.  ONE barrier per phase (pre-MFMA only).
#define TILE(bI, oI, BVLO, BVHI, STG0, STG1, STG2, STG3, VMW, DO_PREF) do { \
    /* p0: issue B-half1 -> BVHI; stage; barrier; Q(0,0) = av0 . BVLO */ \
    LOAD_BV(BVHI, bI, 1); STG0; \
    BARRIER(); MFMA_Q(av0, BVLO, 0, 0); \
    /* p1: issue A-half1 -> av1; stage; barrier; Q(0,1) = av0 . BVHI */ \
    LOAD_AV(av1, bI, 1); STG1; \
    BARRIER(); MFMA_Q(av0, BVHI, 0, 1); \
    /* p2: stage; barrier; Q(1,1) = av1 . BVHI */ \
    STG2; \
    BARRIER(); MFMA_Q(av1, BVHI, 1, 1); \
    /* p3: stage; vmcnt; barrier; prefetch next tile's A0 -> av0, B0 -> BVHI; Q(1,0) */ \
    STG3; VMW; \
    BARRIER(); \
    if (DO_PREF) { LOAD_AV(av0, oI, 0); LOAD_BV(BVHI, oI, 0); } \
    MFMA_Q(av1, BVLO, 1, 0); \
} while (0)

    // prologue: stage tile0 fully + tile1's A0,B1,A1 (B0(1) comes at t0-p0).
    // vmcnt(6): 14 outstanding -> retires the oldest 8 = ALL of tile0.
    STAGE_A(0, 0, 0);  STAGE_B(0, 0, 0);  STAGE_B(0, 1, 0);  STAGE_A(0, 1, 0);
    STAGE_A(1, 0, 64); STAGE_B(1, 1, 64); STAGE_A(1, 1, 64);
    WAIT_VM(6);
    BARRIER();
    LOAD_AV(av0, 0, 0); LOAD_BV(bv0, 0, 0);

    // tiles 0..61: steady staging (STG0 -> t+1's B0, STG1-3 -> t+2's A0,B1,A1), vmcnt(6)@p3.
#pragma unroll 1
    for (int tp = 0; tp < 31; ++tp) {
        const int kt = tp * 128;
        TILE(0, 1, bv0, bv1, STAGE_B(1, 0, kt + 64),  STAGE_A(0, 0, kt + 128),
                             STAGE_B(0, 1, kt + 128), STAGE_A(0, 1, kt + 128), WAIT_VM(6), 1);
        TILE(1, 0, bv1, bv0, STAGE_B(0, 0, kt + 128), STAGE_A(1, 0, kt + 192),
                             STAGE_B(1, 1, kt + 192), STAGE_A(1, 1, kt + 192), WAIT_VM(6), 1);
    }
    // t=62: stage only B0(63); drain everything; prefetch t63.  t=63: pure compute.
    TILE(0, 1, bv0, bv1, STAGE_B(1, 0, 4032), (void)0, (void)0, (void)0, WAIT_VM(0), 1);
    TILE(1, 0, bv1, bv0, (void)0, (void)0, (void)0, (void)0, (void)0, 0);

    // epilogue: C/D layout col=lane&15, row=q*4+reg (verified)
    float bb[2][2];
#pragma unroll
    for (int nh = 0; nh < 2; ++nh)
#pragma unroll
        for (int nj = 0; nj < 2; ++nj)
            bb[nh][nj] = bias[n0 + nh * 128 + wc * 32 + nj * 16 + ml];

#pragma unroll
    for (int mh = 0; mh < 2; ++mh)
#pragma unroll
        for (int nh = 0; nh < 2; ++nh)
#pragma unroll
            for (int mi = 0; mi < 4; ++mi)
#pragma unroll
                for (int nj = 0; nj < 2; ++nj) {
                    const int gc  = n0 + nh * 128 + wc * 32 + nj * 16 + ml;
                    const int gr0 = m0 + mh * 128 + wr * 64 + mi * 16 + q * 4;
#pragma unroll
                    for (int r = 0; r < 4; ++r)
                        out[(size_t)(gr0 + r) * 4096 + gc] = acc[mh][nh][mi][nj][r] + bb[nh][nj];
                }
}

// ---------------------------------------------------------------- fp32 fallback (only if ws too small)
__global__ __launch_bounds__(256) void gemm_f32_fallback(const float* __restrict__ x,
                                                         const float* __restrict__ W,
                                                         const float* __restrict__ bias,
                                                         float* __restrict__ out) {
    __shared__ float As[32][33];
    __shared__ float Bs[32][33];
    const int tx = threadIdx.x & 31, ty = threadIdx.x >> 5;   // ty 0..7
    const int m0 = blockIdx.y * 32, n0 = blockIdx.x * 32;
    float acc[4] = {0.f, 0.f, 0.f, 0.f};
    for (int k0 = 0; k0 < 4096; k0 += 32) {
#pragma unroll
        for (int i = 0; i < 4; ++i) {
            As[ty + 8 * i][tx] = x[(size_t)(m0 + ty + 8 * i) * 4096 + k0 + tx];
            Bs[ty + 8 * i][tx] = W[(size_t)(n0 + ty + 8 * i) * 4096 + k0 + tx];
        }
        __syncthreads();
#pragma unroll 8
        for (int kk = 0; kk < 32; ++kk) {
            const float bv_ = Bs[tx][kk];
#pragma unroll
            for (int i = 0; i < 4; ++i) acc[i] += As[ty + 8 * i][kk] * bv_;
        }
        __syncthreads();
    }
#pragma unroll
    for (int i = 0; i < 4; ++i)
        out[(size_t)(m0 + ty + 8 * i) * 4096 + n0 + tx] = acc[i] + bias[n0 + tx];
}

// ---------------------------------------------------------------- launch
extern "C" void kernel_launch(void* const* d_in, const int* in_sizes, int n_in,
                              void* d_out, int out_size, void* d_ws, size_t ws_size,
                              hipStream_t stream) {
    const float* x = (const float*)d_in[0];   // [8192, 4096]
    const float* W = (const float*)d_in[1];   // [4096, 4096]
    const float* b = (const float*)d_in[2];   // [4096]
    float* out = (float*)d_out;               // [8192, 4096]

    constexpr size_t T = 8192, DIN = 4096, DOUT = 4096;
    const size_t nx = T * DIN, nw = DOUT * DIN;

    if (ws_size >= (nx + nw) * sizeof(unsigned short)) {
        unsigned short* xbf = (unsigned short*)d_ws;
        unsigned short* wbf = xbf + nx;
        cast_both<<<24576, 256, 0, stream>>>((const f32x4*)x, (u32x4*)xbf,
                                             (const f32x4*)W, (u32x4*)wbf);
        // 256x256 tiles: 32 x 16 = 512 blocks, 512 threads
        gemm256<<<512, 512, 0, stream>>>(xbf, wbf, b, out);
    } else {
        dim3 grid(DOUT / 32, T / 32);
        gemm_f32_fallback<<<grid, 256, 0, stream>>>(x, W, b, out);
    }
}